// Round 16
// baseline (56.698 us; speedup 1.0000x reference)
//
#include <hip/hip_runtime.h>
#include <hip/hip_bf16.h>

#define BB 2
#define SS 1024
#define DD 256

typedef __attribute__((ext_vector_type(8))) short bf16x8;
typedef __attribute__((ext_vector_type(4))) float f32x4;

__device__ __forceinline__ unsigned short f2bf(float f) {
    __hip_bfloat16 h = __float2bfloat16(f);
    return *reinterpret_cast<unsigned short*>(&h);
}
__device__ __forceinline__ float bf2f(unsigned short u) {
    __hip_bfloat16 h;
    *reinterpret_cast<unsigned short*>(&h) = u;
    return __bfloat162float(h);
}
__device__ __forceinline__ bf16x8 cvt8(float4 f0, float4 f1) {
    bf16x8 o;
    o[0] = (short)f2bf(f0.x); o[1] = (short)f2bf(f0.y);
    o[2] = (short)f2bf(f0.z); o[3] = (short)f2bf(f0.w);
    o[4] = (short)f2bf(f1.x); o[5] = (short)f2bf(f1.y);
    o[6] = (short)f2bf(f1.z); o[7] = (short)f2bf(f1.w);
    return o;
}

// ---------------------------------------------------------------------------
// Kernel 0: fp32->bf16 conversion of the four weight matrices only.
// 32768 units (8 elements each), 128 blocks. x is converted in-register by
// the consumers (4-6x redundancy is cheap VALU; W's 128x was the R7 killer).
// ---------------------------------------------------------------------------
__global__ __launch_bounds__(256) void cvt_w(
    const float* __restrict__ Wq, const float* __restrict__ Wk,
    const float* __restrict__ Wv, const float* __restrict__ Wo,
    unsigned short* __restrict__ Wqb, unsigned short* __restrict__ Wkb,
    unsigned short* __restrict__ Wvb, unsigned short* __restrict__ Wob)
{
    const int u = blockIdx.x * 256 + threadIdx.x;   // unit = 8 elements
    const float* src;
    unsigned short* dst;
    int base;
    if (u < 8192)       { src = Wq; dst = Wqb; base = u; }          // 65536/8
    else if (u < 16384) { src = Wk; dst = Wkb; base = u - 8192; }
    else if (u < 24576) { src = Wv; dst = Wvb; base = u - 16384; }
    else                { src = Wo; dst = Wob; base = u - 24576; }
    const float4* s4 = (const float4*)src + (size_t)base * 2;
    *(bf16x8*)(dst + (size_t)base * 8) = cvt8(s4[0], s4[1]);
}

// ---------------------------------------------------------------------------
// Kernel 1: K,V projection via MFMA, column-split x2 (R15 structure minus Q).
// grid = 128 tiles x 2 mats x 2 col-halves = 512 blocks (2 blocks/CU).
// A-frags from fp32 x, converted in-register (same values as the old xb path).
// K: row-major Kb + kk partial norms [2][rows]. V: VB fragment layout.
// ---------------------------------------------------------------------------
__global__ __launch_bounds__(256, 2) void kv_mfma(
    const float* __restrict__ x,
    const unsigned short* __restrict__ Wkb, const float* __restrict__ bk,
    const unsigned short* __restrict__ Wvb, const float* __restrict__ bv,
    unsigned short* __restrict__ Kb, unsigned short* __restrict__ VB,
    float* __restrict__ kk)   // [2][BB*SS] partials
{
    __shared__ float red[4][16];
    const int t = threadIdx.x;
    const int w = t >> 6, l = t & 63, lr = l & 15, lc = l >> 4;
    const int bx = blockIdx.x;
    const int mat = bx & 1;                  // 0=K 1=V
    const int rest = bx >> 1;
    const int tile = rest >> 1;
    const int ch = rest & 1;                 // column half
    const int r0 = tile * 16;
    const int b = r0 >> 10;
    const int s_in_base = r0 & (SS - 1);
    const size_t rows = (size_t)BB * SS;

    const unsigned short* W = (mat == 0) ? Wkb : Wvb;
    const float* bias       = (mat == 0) ? bk  : bv;

    // A-frags: in-register cvt from fp32 x
    bf16x8 af[8];
#pragma unroll
    for (int db = 0; db < 8; ++db) {
        const float* xp = x + (size_t)(r0 + lr) * DD + db * 32 + 8 * lc;
        af[db] = cvt8(*(const float4*)(xp), *(const float4*)(xp + 4));
    }

    float nrm[4] = {0.f, 0.f, 0.f, 0.f};

#pragma unroll
    for (int cb = 0; cb < 2; ++cb) {
        const int jb = 128 * ch + 32 * w + 16 * cb;
        f32x4 acc = {0.f, 0.f, 0.f, 0.f};
#pragma unroll
        for (int db = 0; db < 8; ++db) {
            bf16x8 bf = *(const bf16x8*)(W + (size_t)(jb + lr) * DD + db * 32 + 8 * lc);
            acc = __builtin_amdgcn_mfma_f32_16x16x32_bf16(af[db], bf, acc, 0, 0, 0);
        }
        const float bv_ = bias[jb + lr];
#pragma unroll
        for (int r = 0; r < 4; ++r) {
            const int srow = r0 + lc * 4 + r;     // C/D: row=(l>>4)*4+r, col=l%16
            const float v = acc[r] + bv_;
            const unsigned short h = f2bf(v);
            if (mat == 0) {
                Kb[(size_t)srow * DD + jb + lr] = h;
                const float hv = bf2f(h); nrm[r] += hv * hv;
            } else {
                // VB layout: tile(b, kb32=s/32, db16=d/16) of 1024B
                const int s_in = s_in_base + lc * 4 + r;
                const int kb32 = s_in >> 5;
                const int kslot = (s_in >> 3) & 3;
                const int jj = s_in & 7;
                const int db16 = ch * 8 + 2 * w + cb;
                const size_t off = ((size_t)((b * 32 + kb32) * 16 + db16) << 9)
                                 + ((kslot * 16 + lr) << 3) + jj;
                VB[off] = h;
            }
        }
    }

    if (mat == 0) {
#pragma unroll
        for (int r = 0; r < 4; ++r) {
            float n = nrm[r];
#pragma unroll
            for (int m = 1; m < 16; m <<= 1) n += __shfl_xor(n, m, 64);
            if (lr == 0) red[w][lc * 4 + r] = n;
        }
        __syncthreads();
        if (t < 16)
            kk[(size_t)ch * rows + r0 + t] =
                red[0][t] + red[1][t] + red[2][t] + red[3][t];
    }
}

// ---------------------------------------------------------------------------
// Kernel 2: FUSED Q-projection + attention + output projection.
// grid = 128 blocks (16-row q-tile), 512 threads (8 waves).
// Prologue: Q = x@Wq.T + bq computed IN-BLOCK (x in-reg cvt; Wqb bf16),
//   staged in LDS Q_s[16][264] (pad -> 8-way bank spread), qq norms reduced
//   in-block. Kills the Qb global round-trip and the qq buffer.
// Then phases A/B/C as R13/R15 (QK^T+exp -> PV -> out-proj).
// Alias: Q_s lives in P_s[0..]; all qf reads complete before the barrier
// that precedes any P_s write.
// ---------------------------------------------------------------------------
__global__ __launch_bounds__(512, 2) void attn_out_mfma(
    const float* __restrict__ x,
    const unsigned short* __restrict__ Wqb, const float* __restrict__ bq,
    const unsigned short* __restrict__ Kb, const unsigned short* __restrict__ VB,
    const float* __restrict__ kk,                       // [2][rows]
    const unsigned short* __restrict__ Wob, const float* __restrict__ bo,
    float* __restrict__ out)
{
    __shared__ __align__(16) unsigned short P_s[16 * 1024];  // 32 KB
    __shared__ float kk_s[SS];                               // 4 KB
    __shared__ float qq_s[16];
    __shared__ float es_red[8][16];
    __shared__ float inv_s[16];
    unsigned short* Q_s   = P_s;     // prologue staging: [16][264] padded
    unsigned short* att_s = P_s;     // post-PV staging:  [16][264] padded

    const int t = threadIdx.x;
    const int w = t >> 6, l = t & 63, lr = l & 15, lc = l >> 4;
    const int rowbase = blockIdx.x * 16;       // global row
    const int b = rowbase >> 10;
    const size_t rows = (size_t)BB * SS;

    kk_s[t]       = kk[b * SS + t]       + kk[rows + b * SS + t];
    kk_s[t + 512] = kk[b * SS + t + 512] + kk[rows + b * SS + t + 512];

    // ---- Prologue: Q = x@Wq.T + bq for these 16 rows ----
    bf16x8 xf[8];
#pragma unroll
    for (int db = 0; db < 8; ++db) {
        const float* xp = x + (size_t)(rowbase + lr) * DD + db * 32 + 8 * lc;
        xf[db] = cvt8(*(const float4*)(xp), *(const float4*)(xp + 4));
    }
    float nrm[4] = {0.f, 0.f, 0.f, 0.f};
#pragma unroll
    for (int cb = 0; cb < 2; ++cb) {
        const int jb = 32 * w + 16 * cb;
        f32x4 acc = {0.f, 0.f, 0.f, 0.f};
#pragma unroll
        for (int db = 0; db < 8; ++db) {
            bf16x8 bf = *(const bf16x8*)(Wqb + (size_t)(jb + lr) * DD + db * 32 + 8 * lc);
            acc = __builtin_amdgcn_mfma_f32_16x16x32_bf16(xf[db], bf, acc, 0, 0, 0);
        }
        const float bqv = bq[jb + lr];
#pragma unroll
        for (int r = 0; r < 4; ++r) {
            const int row = lc * 4 + r;           // C/D mapping
            const float v = acc[r] + bqv;
            const unsigned short h = f2bf(v);
            Q_s[row * 264 + jb + lr] = h;
            const float hv = bf2f(h); nrm[r] += hv * hv;
        }
    }
#pragma unroll
    for (int r = 0; r < 4; ++r) {
        float n = nrm[r];
#pragma unroll
        for (int m = 1; m < 16; m <<= 1) n += __shfl_xor(n, m, 64);
        if (lr == 0) es_red[w][lc * 4 + r] = n;
    }
    __syncthreads();            // Q_s + es_red complete
    if (t < 16) {
        float s = 0.f;
#pragma unroll
        for (int ww = 0; ww < 8; ++ww) s += es_red[ww][t];
        qq_s[t] = s;
    }
    // Q A-frags from LDS (pad 264 -> 8-way bank spread, ~2-way conflict)
    bf16x8 qf[8];
#pragma unroll
    for (int db = 0; db < 8; ++db)
        qf[db] = *(const bf16x8*)(Q_s + lr * 264 + db * 32 + 8 * lc);
    __syncthreads();            // all qf reads done; P_s may be overwritten

    // ---- Phase A: QK^T + exp; wave w owns k-cols [128w, 128w+128) ----
    float psum[4] = {0.f, 0.f, 0.f, 0.f};
#pragma unroll
    for (int kbi = 0; kbi < 8; ++kbi) {
        const int kb = 128 * w + 16 * kbi;
        f32x4 acc = {0.f, 0.f, 0.f, 0.f};
#pragma unroll
        for (int db = 0; db < 8; ++db) {
            bf16x8 kf = *(const bf16x8*)(
                Kb + (size_t)(b * SS + kb + lr) * DD + db * 32 + 8 * lc);
            acc = __builtin_amdgcn_mfma_f32_16x16x32_bf16(qf[db], kf, acc, 0, 0, 0);
        }
        const int kcol = kb + lr;
        const float kkv = kk_s[kcol];
#pragma unroll
        for (int r = 0; r < 4; ++r) {
            const int qi = lc * 4 + r;
            const float d2 = fmaxf(qq_s[qi] + kkv - 2.f * acc[r], 0.f);
            const float e = __expf(-sqrtf(d2) * 0.0625f);
            psum[r] += e;
            P_s[qi * 1024 + (kcol ^ ((qi & 7) << 3))] = f2bf(e);
        }
    }
    // per-row sums
#pragma unroll
    for (int r = 0; r < 4; ++r) {
        float s = psum[r];
#pragma unroll
        for (int m = 1; m < 16; m <<= 1) s += __shfl_xor(s, m, 64);
        if (lr == 0) es_red[w][lc * 4 + r] = s;
    }
    __syncthreads();            // publishes P_s + es_red
    if (t < 16) {
        float s = 0.f;
#pragma unroll
        for (int ww = 0; ww < 8; ++ww) s += es_red[ww][t];
        inv_s[t] = 1.f / s;
    }

    // ---- Phase B: PV; wave w owns d-cols [32w, 32w+32) ----
    f32x4 acc2[2];
#pragma unroll
    for (int i = 0; i < 2; ++i) acc2[i] = (f32x4){0.f, 0.f, 0.f, 0.f};

#pragma unroll
    for (int ki = 0; ki < 32; ++ki) {
        bf16x8 pf = *(const bf16x8*)(
            P_s + lr * 1024 + ((32 * ki + 8 * lc) ^ ((lr & 7) << 3)));
        const size_t tbase =
            ((size_t)((b * 32 + ki) * 16 + 2 * w) << 9) + l * 8;
#pragma unroll
        for (int dbi = 0; dbi < 2; ++dbi) {
            bf16x8 vf = *(const bf16x8*)(VB + tbase + ((size_t)dbi << 9));
            acc2[dbi] = __builtin_amdgcn_mfma_f32_16x16x32_bf16(pf, vf, acc2[dbi], 0, 0, 0);
        }
    }
    __syncthreads();            // all P_s reads done; inv_s visible

    // normalize + write att (bf16) to padded LDS [16][264]
#pragma unroll
    for (int dbi = 0; dbi < 2; ++dbi)
#pragma unroll
        for (int r = 0; r < 4; ++r) {
            const int qi = lc * 4 + r;
            att_s[qi * 264 + 32 * w + 16 * dbi + lr] =
                f2bf(acc2[dbi][r] * inv_s[qi]);
        }
    __syncthreads();

    // ---- Phase C: out-proj; wave w owns out-cols [32w, 32w+32) ----
    bf16x8 af[8];
#pragma unroll
    for (int db = 0; db < 8; ++db)
        af[db] = *(const bf16x8*)(att_s + lr * 264 + db * 32 + 8 * lc);

#pragma unroll
    for (int cb = 0; cb < 2; ++cb) {
        const int jb = 32 * w + 16 * cb;
        f32x4 acc = {0.f, 0.f, 0.f, 0.f};
#pragma unroll
        for (int db = 0; db < 8; ++db) {
            bf16x8 bf = *(const bf16x8*)(Wob + (size_t)(jb + lr) * DD + db * 32 + 8 * lc);
            acc = __builtin_amdgcn_mfma_f32_16x16x32_bf16(af[db], bf, acc, 0, 0, 0);
        }
        const float bov = bo[jb + lr];
#pragma unroll
        for (int r = 0; r < 4; ++r)
            out[(size_t)(rowbase + lc * 4 + r) * DD + jb + lr] = acc[r] + bov;
    }
}

// ---------------------------------------------------------------------------
extern "C" void kernel_launch(void* const* d_in, const int* in_sizes, int n_in,
                              void* d_out, int out_size, void* d_ws, size_t ws_size,
                              hipStream_t stream) {
    const float* x  = (const float*)d_in[0];
    const float* Wq = (const float*)d_in[1];
    const float* bq = (const float*)d_in[2];
    const float* Wk = (const float*)d_in[3];
    const float* bk = (const float*)d_in[4];
    const float* Wv = (const float*)d_in[5];
    const float* bv = (const float*)d_in[6];
    const float* Wo = (const float*)d_in[7];
    const float* bo = (const float*)d_in[8];
    float* out = (float*)d_out;

    // ws layout (bf16): Kb | VB | Wqb | Wkb | Wvb | Wob || kk[2][rows] (fp32)
    const size_t rows = (size_t)BB * SS;            // 2048
    unsigned short* Kb  = (unsigned short*)d_ws;
    unsigned short* VB  = Kb + rows * DD;
    unsigned short* Wqb = VB + rows * DD;
    unsigned short* Wkb = Wqb + (size_t)DD * DD;
    unsigned short* Wvb = Wkb + (size_t)DD * DD;
    unsigned short* Wob = Wvb + (size_t)DD * DD;
    float* kk    = (float*)(Wob + (size_t)DD * DD);  // 2*rows

    cvt_w<<<128, 256, 0, stream>>>(Wq, Wk, Wv, Wo, Wqb, Wkb, Wvb, Wob);
    kv_mfma<<<512, 256, 0, stream>>>(x, Wkb, bk, Wvb, bv, Kb, VB, kk);
    attn_out_mfma<<<(int)(rows / 16), 512, 0, stream>>>(
        x, Wqb, bq, Kb, VB, kk, Wob, bo, out);
}

// Round 17
// 51.543 us; speedup vs baseline: 1.1000x; 1.1000x over previous
//
#include <hip/hip_runtime.h>
#include <hip/hip_bf16.h>

#define BB 2
#define SS 1024
#define DD 256
#define NCH 2           // k-halves in attn
#define KCH 512         // k-chunk size

typedef __attribute__((ext_vector_type(8))) short bf16x8;
typedef __attribute__((ext_vector_type(4))) float f32x4;

__device__ __forceinline__ unsigned short f2bf(float f) {
    __hip_bfloat16 h = __float2bfloat16(f);
    return *reinterpret_cast<unsigned short*>(&h);
}
__device__ __forceinline__ float bf2f(unsigned short u) {
    __hip_bfloat16 h;
    *reinterpret_cast<unsigned short*>(&h) = u;
    return __bfloat162float(h);
}
__device__ __forceinline__ bf16x8 cvt8(float4 f0, float4 f1) {
    bf16x8 o;
    o[0] = (short)f2bf(f0.x); o[1] = (short)f2bf(f0.y);
    o[2] = (short)f2bf(f0.z); o[3] = (short)f2bf(f0.w);
    o[4] = (short)f2bf(f1.x); o[5] = (short)f2bf(f1.y);
    o[6] = (short)f2bf(f1.z); o[7] = (short)f2bf(f1.w);
    return o;
}

// ---------------------------------------------------------------------------
// Kernel 0: fp32->bf16 conversion of the four weight matrices (R15 verbatim).
// ---------------------------------------------------------------------------
__global__ __launch_bounds__(256) void cvt_w(
    const float* __restrict__ Wq, const float* __restrict__ Wk,
    const float* __restrict__ Wv, const float* __restrict__ Wo,
    unsigned short* __restrict__ Wqb, unsigned short* __restrict__ Wkb,
    unsigned short* __restrict__ Wvb, unsigned short* __restrict__ Wob)
{
    const int u = blockIdx.x * 256 + threadIdx.x;   // unit = 8 elements
    const float* src;
    unsigned short* dst;
    int base;
    if (u < 8192)       { src = Wq; dst = Wqb; base = u; }
    else if (u < 16384) { src = Wk; dst = Wkb; base = u - 8192; }
    else if (u < 24576) { src = Wv; dst = Wvb; base = u - 16384; }
    else                { src = Wo; dst = Wob; base = u - 24576; }
    const float4* s4 = (const float4*)src + (size_t)base * 2;
    *(bf16x8*)(dst + (size_t)base * 8) = cvt8(s4[0], s4[1]);
}

// ---------------------------------------------------------------------------
// Kernel 1: Q,K,V projection via MFMA, column-split x2 (R15 verbatim).
// grid = 128 tiles x 3 mats x 2 col-halves = 768 blocks (3 blocks/CU).
// qq/kk stored as [2][rows] partials; consumers sum the halves.
// ---------------------------------------------------------------------------
__global__ __launch_bounds__(256, 2) void qkv_mfma(
    const float* __restrict__ x,
    const unsigned short* __restrict__ Wqb, const float* __restrict__ bq,
    const unsigned short* __restrict__ Wkb, const float* __restrict__ bk,
    const unsigned short* __restrict__ Wvb, const float* __restrict__ bv,
    unsigned short* __restrict__ Qb, unsigned short* __restrict__ Kb,
    unsigned short* __restrict__ VB,
    float* __restrict__ qq, float* __restrict__ kk)   // [2][BB*SS] partials
{
    __shared__ float red[4][16];
    const int t = threadIdx.x;
    const int w = t >> 6, l = t & 63, lr = l & 15, lc = l >> 4;
    const int bx = blockIdx.x;
    const int mat = bx % 3;
    const int rest = bx / 3;
    const int tile = rest >> 1;
    const int ch = rest & 1;                 // column half
    const int r0 = tile * 16;
    const int b = r0 >> 10;
    const int s_in_base = r0 & (SS - 1);
    const size_t rows = (size_t)BB * SS;

    const unsigned short* W = (mat == 0) ? Wqb : (mat == 1) ? Wkb : Wvb;
    const float* bias       = (mat == 0) ? bq  : (mat == 1) ? bk  : bv;

    // A-frags: in-register cvt from fp32 x
    bf16x8 af[8];
#pragma unroll
    for (int db = 0; db < 8; ++db) {
        const float* xp = x + (size_t)(r0 + lr) * DD + db * 32 + 8 * lc;
        af[db] = cvt8(*(const float4*)(xp), *(const float4*)(xp + 4));
    }

    float nrm[4] = {0.f, 0.f, 0.f, 0.f};

#pragma unroll
    for (int cb = 0; cb < 2; ++cb) {
        const int jb = 128 * ch + 32 * w + 16 * cb;
        f32x4 acc = {0.f, 0.f, 0.f, 0.f};
#pragma unroll
        for (int db = 0; db < 8; ++db) {
            bf16x8 bf = *(const bf16x8*)(W + (size_t)(jb + lr) * DD + db * 32 + 8 * lc);
            acc = __builtin_amdgcn_mfma_f32_16x16x32_bf16(af[db], bf, acc, 0, 0, 0);
        }
        const float bv_ = bias[jb + lr];
#pragma unroll
        for (int r = 0; r < 4; ++r) {
            const int srow = r0 + lc * 4 + r;     // C/D: row=(l>>4)*4+r, col=l%16
            const float v = acc[r] + bv_;
            const unsigned short h = f2bf(v);
            if (mat == 0) {
                Qb[(size_t)srow * DD + jb + lr] = h;
                const float hv = bf2f(h); nrm[r] += hv * hv;
            } else if (mat == 1) {
                Kb[(size_t)srow * DD + jb + lr] = h;
                const float hv = bf2f(h); nrm[r] += hv * hv;
            } else {
                // VB layout: tile(b, kb32=s/32, db16=d/16) of 1024B
                const int s_in = s_in_base + lc * 4 + r;
                const int kb32 = s_in >> 5;
                const int kslot = (s_in >> 3) & 3;
                const int jj = s_in & 7;
                const int db16 = ch * 8 + 2 * w + cb;
                const size_t off = ((size_t)((b * 32 + kb32) * 16 + db16) << 9)
                                 + ((kslot * 16 + lr) << 3) + jj;
                VB[off] = h;
            }
        }
    }

    if (mat < 2) {
#pragma unroll
        for (int r = 0; r < 4; ++r) {
            float n = nrm[r];
#pragma unroll
            for (int m = 1; m < 16; m <<= 1) n += __shfl_xor(n, m, 64);
            if (lr == 0) red[w][lc * 4 + r] = n;
        }
        __syncthreads();
        if (t < 16) {
            const float s = red[0][t] + red[1][t] + red[2][t] + red[3][t];
            if (mat == 0) qq[(size_t)ch * rows + r0 + t] = s;
            else          kk[(size_t)ch * rows + r0 + t] = s;
        }
    }
}

// ---------------------------------------------------------------------------
// Kernel 2: half-k partial attention (chunked geometry = proven 14.7us class).
// grid = 128 qtiles x 2 k-halves = 256 blocks (1/CU, full coverage),
// 512 threads (8 waves). Per block streams 512KB of K/V (vs 1MB fused) and
// per-CU load matches R8's 14.7us kernel (2 blk x 256KB there = 1 x 512KB).
// QK^T: wave w owns local k-cols [64w, 64w+64): 4 kbi x 8 db MFMA.
// P_s[16][512] bf16, XOR-swizzled (proven formula; row stride 1024B).
// PV: wave w owns d-cols [32w, 32w+32): 16 ki x 2 dbi MFMA.
// Outputs fp32 Opart[2][rows][256] (4MB total, 8x less than R8) + esum[2].
// ---------------------------------------------------------------------------
__global__ __launch_bounds__(512, 2) void attn_half_mfma(
    const unsigned short* __restrict__ Qb, const unsigned short* __restrict__ Kb,
    const unsigned short* __restrict__ VB,
    const float* __restrict__ qq, const float* __restrict__ kk,  // [2][rows]
    float* __restrict__ Opart, float* __restrict__ esum)
{
    __shared__ __align__(16) unsigned short P_s[16 * KCH];   // 16 KB
    __shared__ float kk_s[KCH];                              // 2 KB
    __shared__ float qq_s[16];
    __shared__ float es_red[8][16];

    const int t = threadIdx.x;
    const int w = t >> 6, l = t & 63, lr = l & 15, lc = l >> 4;
    const int qtile = blockIdx.x >> 1;
    const int c = blockIdx.x & 1;              // k-half
    const int rowbase = qtile * 16;            // global row
    const int b = rowbase >> 10;
    const int s0 = c * KCH;                    // chunk start within batch
    const size_t rows = (size_t)BB * SS;

    kk_s[t] = kk[b * SS + s0 + t] + kk[rows + b * SS + s0 + t];
    if (t < 16) qq_s[t] = qq[rowbase + t] + qq[rows + rowbase + t];

    // Q A-frags: lane(row=l%16, 8 contiguous d)
    bf16x8 qf[8];
#pragma unroll
    for (int db = 0; db < 8; ++db)
        qf[db] = *(const bf16x8*)(Qb + (size_t)(rowbase + lr) * DD + db * 32 + 8 * lc);

    __syncthreads();

    // ---- QK^T + exp: wave w owns local k-cols [64w, 64w+64) ----
    float psum[4] = {0.f, 0.f, 0.f, 0.f};
#pragma unroll
    for (int kbi = 0; kbi < 4; ++kbi) {
        const int kb = 64 * w + 16 * kbi;      // local k-col base
        f32x4 acc = {0.f, 0.f, 0.f, 0.f};
#pragma unroll
        for (int db = 0; db < 8; ++db) {
            bf16x8 kf = *(const bf16x8*)(
                Kb + (size_t)(b * SS + s0 + kb + lr) * DD + db * 32 + 8 * lc);
            acc = __builtin_amdgcn_mfma_f32_16x16x32_bf16(qf[db], kf, acc, 0, 0, 0);
        }
        const int kcol = kb + lr;              // local, in [0, 512)
        const float kkv = kk_s[kcol];
#pragma unroll
        for (int r = 0; r < 4; ++r) {
            const int qi = lc * 4 + r;
            const float d2 = fmaxf(qq_s[qi] + kkv - 2.f * acc[r], 0.f);
            const float e = __expf(-sqrtf(d2) * 0.0625f);
            psum[r] += e;
            P_s[qi * KCH + (kcol ^ ((qi & 7) << 3))] = f2bf(e);
        }
    }
    // per-row e-sums: reduce across lr, then across 8 waves via LDS
#pragma unroll
    for (int r = 0; r < 4; ++r) {
        float s = psum[r];
#pragma unroll
        for (int m = 1; m < 16; m <<= 1) s += __shfl_xor(s, m, 64);
        if (lr == 0) es_red[w][lc * 4 + r] = s;
    }
    __syncthreads();   // publishes P_s + es_red
    if (t < 16) {
        float s = 0.f;
#pragma unroll
        for (int ww = 0; ww < 8; ++ww) s += es_red[ww][t];
        esum[(size_t)c * rows + rowbase + t] = s;
    }

    // ---- PV: wave w owns d-cols [32w, 32w+32) ----
    f32x4 acc2[2];
#pragma unroll
    for (int i = 0; i < 2; ++i) acc2[i] = (f32x4){0.f, 0.f, 0.f, 0.f};

#pragma unroll
    for (int ki = 0; ki < KCH / 32; ++ki) {    // 16 iters
        bf16x8 pf = *(const bf16x8*)(
            P_s + lr * KCH + ((32 * ki + 8 * lc) ^ ((lr & 7) << 3)));
        const size_t tbase =
            ((size_t)((b * 32 + c * (KCH / 32) + ki) * 16 + 2 * w) << 9) + l * 8;
#pragma unroll
        for (int dbi = 0; dbi < 2; ++dbi) {
            bf16x8 vf = *(const bf16x8*)(VB + tbase + ((size_t)dbi << 9));
            acc2[dbi] = __builtin_amdgcn_mfma_f32_16x16x32_bf16(pf, vf, acc2[dbi], 0, 0, 0);
        }
    }
#pragma unroll
    for (int dbi = 0; dbi < 2; ++dbi)
#pragma unroll
        for (int r = 0; r < 4; ++r)
            Opart[((size_t)c * rows + rowbase + lc * 4 + r) * DD
                  + 32 * w + 16 * dbi + lr] = acc2[dbi][r];
}

// ---------------------------------------------------------------------------
// Kernel 3: combine halves + output projection via MFMA (R8's proven kernel,
// NCH=2). grid = 128 qtiles x 4 col-quarters = 512 blocks, 256 thr.
// Reads only 4MB of Opart total (vs R8's 32MB, the hidden ~15-20us cost).
// ---------------------------------------------------------------------------
__global__ __launch_bounds__(256, 2) void combine_mfma(
    const float* __restrict__ Opart, const float* __restrict__ esum,
    const unsigned short* __restrict__ Wob, const float* __restrict__ bo,
    float* __restrict__ out)
{
    __shared__ float inv_s[16];
    const int t = threadIdx.x;
    const int w = t >> 6, l = t & 63, lr = l & 15, lc = l >> 4;
    const int r0 = (blockIdx.x >> 2) * 16;   // global row
    const int ch = blockIdx.x & 3;           // col quarter
    const size_t rows = (size_t)BB * SS;

    if (t < 16) {
        float d = 0.f;
#pragma unroll
        for (int c = 0; c < NCH; ++c) d += esum[(size_t)c * rows + r0 + t];
        inv_s[t] = 1.f / d;
    }
    __syncthreads();

    const float inv = inv_s[lr];
    bf16x8 af[8];
#pragma unroll
    for (int db = 0; db < 8; ++db) {
        const float* op = Opart + (size_t)(r0 + lr) * DD + db * 32 + 8 * lc;
        float s0 = 0.f, s1 = 0.f, s2 = 0.f, s3 = 0.f;
        float s4 = 0.f, s5 = 0.f, s6 = 0.f, s7 = 0.f;
#pragma unroll
        for (int c = 0; c < NCH; ++c) {
            const float* p = op + (size_t)c * (rows * DD);
            float4 a0 = *(const float4*)(p);
            float4 a1 = *(const float4*)(p + 4);
            s0 += a0.x; s1 += a0.y; s2 += a0.z; s3 += a0.w;
            s4 += a1.x; s5 += a1.y; s6 += a1.z; s7 += a1.w;
        }
        bf16x8 a;
        a[0] = (short)f2bf(s0 * inv); a[1] = (short)f2bf(s1 * inv);
        a[2] = (short)f2bf(s2 * inv); a[3] = (short)f2bf(s3 * inv);
        a[4] = (short)f2bf(s4 * inv); a[5] = (short)f2bf(s5 * inv);
        a[6] = (short)f2bf(s6 * inv); a[7] = (short)f2bf(s7 * inv);
        af[db] = a;
    }

    const int jb = 64 * ch + 16 * w;
    f32x4 acc = {0.f, 0.f, 0.f, 0.f};
#pragma unroll
    for (int db = 0; db < 8; ++db) {
        bf16x8 bf = *(const bf16x8*)(Wob + (size_t)(jb + lr) * DD + db * 32 + 8 * lc);
        acc = __builtin_amdgcn_mfma_f32_16x16x32_bf16(af[db], bf, acc, 0, 0, 0);
    }
    const float bov = bo[jb + lr];
#pragma unroll
    for (int r = 0; r < 4; ++r)
        out[(size_t)(r0 + lc * 4 + r) * DD + jb + lr] = acc[r] + bov;
}

// ---------------------------------------------------------------------------
extern "C" void kernel_launch(void* const* d_in, const int* in_sizes, int n_in,
                              void* d_out, int out_size, void* d_ws, size_t ws_size,
                              hipStream_t stream) {
    const float* x  = (const float*)d_in[0];
    const float* Wq = (const float*)d_in[1];
    const float* bq = (const float*)d_in[2];
    const float* Wk = (const float*)d_in[3];
    const float* bk = (const float*)d_in[4];
    const float* Wv = (const float*)d_in[5];
    const float* bv = (const float*)d_in[6];
    const float* Wo = (const float*)d_in[7];
    const float* bo = (const float*)d_in[8];
    float* out = (float*)d_out;

    // ws layout (bf16): Qb | Kb | VB | Wqb | Wkb | Wvb | Wob ||
    //                   qq[2][rows] | kk[2][rows] | esum[2][rows] | Opart (fp32)
    const size_t rows = (size_t)BB * SS;            // 2048
    unsigned short* Qb  = (unsigned short*)d_ws;
    unsigned short* Kb  = Qb + rows * DD;
    unsigned short* VB  = Kb + rows * DD;
    unsigned short* Wqb = VB + rows * DD;
    unsigned short* Wkb = Wqb + (size_t)DD * DD;
    unsigned short* Wvb = Wkb + (size_t)DD * DD;
    unsigned short* Wob = Wvb + (size_t)DD * DD;
    float* qq    = (float*)(Wob + (size_t)DD * DD);  // 2*rows
    float* kk    = qq + 2 * rows;                    // 2*rows
    float* esum  = kk + 2 * rows;                    // 2*rows
    float* Opart = esum + 2 * rows;                  // 2*rows*DD floats (4MB)

    cvt_w<<<128, 256, 0, stream>>>(Wq, Wk, Wv, Wo, Wqb, Wkb, Wvb, Wob);
    qkv_mfma<<<768, 256, 0, stream>>>(
        x, Wqb, bq, Wkb, bk, Wvb, bv, Qb, Kb, VB, qq, kk);
    attn_half_mfma<<<256, 512, 0, stream>>>(
        Qb, Kb, VB, qq, kk, Opart, esum);
    combine_mfma<<<512, 256, 0, stream>>>(
        Opart, esum, Wob, bo, out);
}